// Round 1
// baseline (1997.741 us; speedup 1.0000x reference)
//
#include <hip/hip_runtime.h>
#include <hip/hip_bf16.h>
#include <stdint.h>

#define NN 100000   // nodes
#define NE 500000   // edges per head
#define NA 4        // angle heads
#define DIM 128     // bond/hidden dim
#define LDA 136     // padded LDS row stride (bf16 elems): +16B breaks bank stride

typedef __attribute__((ext_vector_type(8))) short bf16x8;
typedef __attribute__((ext_vector_type(4))) float f32x4;
typedef unsigned short u16;
typedef unsigned int u32;

__device__ __forceinline__ u16 f2bf(float x) {
    u32 u = __float_as_uint(x);
    u32 r = (u + 0x7fffu + ((u >> 16) & 1u)) >> 16;  // round-to-nearest-even
    return (u16)r;
}
__device__ __forceinline__ float bf2f(u16 h) {
    return __uint_as_float(((u32)h) << 16);
}
__device__ __forceinline__ float fast_tanh(float x) {
    // tanh(x) = 1 - 2/(e^{2x}+1); saturates correctly at +/-inf
    float t = __expf(2.0f * x);
    return 1.0f - __fdividef(2.0f, t + 1.0f);
}

// ---- cast bond_feat fp32 -> bf16 (8 elems/thread) ----
__global__ __launch_bounds__(256) void cast_bond(const float* __restrict__ x,
                                                 u16* __restrict__ y) {
    int i = blockIdx.x * 256 + threadIdx.x;
    if (i >= NN * DIM / 8) return;
    const float4* xv = (const float4*)x;
    float4 a = xv[2 * i], b = xv[2 * i + 1];
    uint4 o;
    o.x = (u32)f2bf(a.x) | ((u32)f2bf(a.y) << 16);
    o.y = (u32)f2bf(a.z) | ((u32)f2bf(a.w) << 16);
    o.z = (u32)f2bf(b.x) | ((u32)f2bf(b.y) << 16);
    o.w = (u32)f2bf(b.z) | ((u32)f2bf(b.w) << 16);
    ((uint4*)y)[i] = o;
}

// ---- pack W [4][256][128] fp32 -> WbT [8 slabs][128 out][128 in] bf16 ----
// slab = k*2 + t ; t=0: x_i rows (din 0..127), t=1: x_j rows (din 128..255)
__global__ __launch_bounds__(256) void pack_w(const float* __restrict__ W,
                                              u16* __restrict__ WbT) {
    int i = blockIdx.x * 256 + threadIdx.x;  // 131072 total
    int d = i & 127;
    int o = (i >> 7) & 127;
    int st = i >> 14;  // slab
    // W[k][t*128+d][o] = W[(st*128 + d)*128 + o]  (since k*256 = (k*2)*128)
    WbT[i] = f2bf(W[(size_t)(st * 128 + d) * 128 + o]);
}

// ---- Y[slab][node][128] bf16 = bond @ Wslab (+bias on t==0 slabs) ----
__global__ __launch_bounds__(256) void gemm_y(const u16* __restrict__ bondB,
                                              const u16* __restrict__ WbT,
                                              const float* __restrict__ bias,
                                              u16* __restrict__ Y) {
    __shared__ __align__(16) u16 As[64 * LDA];
    __shared__ __align__(16) u16 Bs[128 * LDA];
    const int slab = blockIdx.y;
    const int node0 = blockIdx.x * 64;
    const int tid = threadIdx.x;

    // stage A tile: 64 nodes x 128 bf16 (16B per thread-chunk)
#pragma unroll
    for (int it = 0; it < 4; ++it) {
        int idx = it * 256 + tid;  // 0..1023
        int row = idx >> 4, ch = idx & 15;
        int gr = node0 + row;
        if (gr >= NN) gr = NN - 1;  // clamp (dup reads ok, stores guarded)
        *(uint4*)&As[row * LDA + ch * 8] = *(const uint4*)&bondB[(size_t)gr * DIM + ch * 8];
    }
    // stage B tile: W^T slab [128 out][128 in]
    const u16* Wslab = WbT + (size_t)slab * DIM * DIM;
#pragma unroll
    for (int it = 0; it < 8; ++it) {
        int idx = it * 256 + tid;  // 0..2047
        int row = idx >> 4, ch = idx & 15;
        *(uint4*)&Bs[row * LDA + ch * 8] = *(const uint4*)&Wslab[idx * 8];
    }
    __syncthreads();

    const int wave = tid >> 6, lane = tid & 63;
    const int m0 = wave * 16;           // 16 node-rows per wave
    const int lrow = lane & 15;         // A row in tile / B out-col
    const int lk8 = (lane >> 4) * 8;    // k-offset base

    f32x4 acc[8] = {};
#pragma unroll
    for (int kk = 0; kk < 4; ++kk) {
        int ko = kk * 32 + lk8;
        bf16x8 a = *(const bf16x8*)&As[(m0 + lrow) * LDA + ko];
#pragma unroll
        for (int nb = 0; nb < 8; ++nb) {
            bf16x8 b = *(const bf16x8*)&Bs[(nb * 16 + lrow) * LDA + ko];
            acc[nb] = __builtin_amdgcn_mfma_f32_16x16x32_bf16(a, b, acc[nb], 0, 0, 0);
        }
    }

    // epilogue: C/D layout col=lane&15, row=(lane>>4)*4+reg
    const int k = slab >> 1, t = slab & 1;
    const int rbase = (lane >> 4) * 4;
#pragma unroll
    for (int nb = 0; nb < 8; ++nb) {
        int o = nb * 16 + lrow;
        float bv = (t == 0) ? bias[k * DIM + o] : 0.0f;
#pragma unroll
        for (int r = 0; r < 4; ++r) {
            int node = node0 + m0 + rbase + r;
            if (node < NN)
                Y[(size_t)slab * NN * DIM + (size_t)node * DIM + o] = f2bf(acc[nb][r] + bv);
        }
    }
}

// ---- edge phase: one wave per (edge, head); lane handles 2 features ----
__global__ __launch_bounds__(256) void edge_kernel(const int* __restrict__ ei,
                                                   const u16* __restrict__ Y,
                                                   const float* __restrict__ bond,
                                                   float* __restrict__ out) {
    const int k = blockIdx.y;
    const int e = blockIdx.x * 4 + (threadIdx.x >> 6);
    const int lane = threadIdx.x & 63;
    const int src = ei[(size_t)(k * 2 + 0) * NE + e];  // j
    const int dst = ei[(size_t)(k * 2 + 1) * NE + e];  // i
    const int f = lane * 2;
    const u32 y1p = *(const u32*)&Y[((size_t)(k * 2 + 0) * NN + dst) * DIM + f];
    const u32 y2p = *(const u32*)&Y[((size_t)(k * 2 + 1) * NN + src) * DIM + f];
    const float2 xj = *(const float2*)&bond[(size_t)src * DIM + f];
    float p0 = bf2f((u16)(y1p & 0xffffu)) + bf2f((u16)(y2p & 0xffffu));
    float p1 = bf2f((u16)(y1p >> 16)) + bf2f((u16)(y2p >> 16));
    float a0 = fast_tanh(p0);
    float a1 = fast_tanh(p1);
    float* op = out + (size_t)dst * (NA * DIM) + k * DIM + f;
    atomicAdd(op, a0 * xj.x);
    atomicAdd(op + 1, a1 * xj.y);
}

// ---- fallback (only if ws is too small): direct per-edge compute ----
__global__ __launch_bounds__(128) void fallback_edge(const float* __restrict__ bond,
                                                     const int* __restrict__ ei,
                                                     const float* __restrict__ W,
                                                     const float* __restrict__ bias,
                                                     float* __restrict__ out) {
    __shared__ float xi[DIM], xj[DIM];
    const int k = blockIdx.y;
    const int e = blockIdx.x;
    const int o = threadIdx.x;
    const int src = ei[(size_t)(k * 2 + 0) * NE + e];
    const int dst = ei[(size_t)(k * 2 + 1) * NE + e];
    xi[o] = bond[(size_t)dst * DIM + o];
    xj[o] = bond[(size_t)src * DIM + o];
    __syncthreads();
    const float* Wk = W + (size_t)k * 2 * DIM * DIM;
    float acc = bias[k * DIM + o];
    for (int din = 0; din < DIM; ++din) {
        acc += xi[din] * Wk[din * DIM + o];
        acc += xj[din] * Wk[(DIM + din) * DIM + o];
    }
    float alpha = fast_tanh(acc);
    atomicAdd(&out[(size_t)dst * (NA * DIM) + k * DIM + o], alpha * xj[o]);
}

extern "C" void kernel_launch(void* const* d_in, const int* in_sizes, int n_in,
                              void* d_out, int out_size, void* d_ws, size_t ws_size,
                              hipStream_t stream) {
    const float* bond = (const float*)d_in[0];
    const int* ei = (const int*)d_in[1];
    const float* W = (const float*)d_in[2];
    const float* bias = (const float*)d_in[3];
    float* out = (float*)d_out;

    hipMemsetAsync(d_out, 0, (size_t)out_size * sizeof(float), stream);

    const size_t wbt_bytes = (size_t)NA * 2 * DIM * DIM * 2;  // 256 KB
    const size_t bondb_bytes = (size_t)NN * DIM * 2;          // 25.6 MB
    const size_t y_bytes = (size_t)NA * 2 * NN * DIM * 2;     // 204.8 MB

    if (ws_size >= wbt_bytes + bondb_bytes + y_bytes) {
        u16* WbT = (u16*)d_ws;
        u16* bondB = (u16*)((char*)d_ws + wbt_bytes);
        u16* Y = (u16*)((char*)d_ws + wbt_bytes + bondb_bytes);
        pack_w<<<dim3(131072 / 256), 256, 0, stream>>>(W, WbT);
        cast_bond<<<dim3((NN * DIM / 8 + 255) / 256), 256, 0, stream>>>(bond, bondB);
        gemm_y<<<dim3((NN + 63) / 64, NA * 2), 256, 0, stream>>>(bondB, WbT, bias, Y);
        edge_kernel<<<dim3(NE / 4, NA), 256, 0, stream>>>(ei, Y, bond, out);
    } else {
        // workspace too small for Y: slow but correct direct path
        fallback_edge<<<dim3(NE, NA), 128, 0, stream>>>(bond, ei, W, bias, out);
    }
}

// Round 2
// 910.280 us; speedup vs baseline: 2.1946x; 2.1946x over previous
//
#include <hip/hip_runtime.h>
#include <hip/hip_bf16.h>
#include <stdint.h>

#define NN 100000   // nodes
#define NE 500000   // edges per head
#define NA 4        // angle heads
#define DIM 128     // bond/hidden dim
#define LDA 136     // padded LDS row stride (bf16 elems)

#define NBINS (NA * NN)          // 400000 (k-major bins)
#define SCAN_CHUNK 1024          // elems per scan block (256 thr x 4)
#define NBLK ((NBINS + SCAN_CHUNK - 1) / SCAN_CHUNK)  // 391

typedef __attribute__((ext_vector_type(8))) short bf16x8;
typedef __attribute__((ext_vector_type(4))) float f32x4;
typedef unsigned short u16;
typedef unsigned int u32;

__device__ __forceinline__ u16 f2bf(float x) {
    u32 u = __float_as_uint(x);
    u32 r = (u + 0x7fffu + ((u >> 16) & 1u)) >> 16;  // RNE
    return (u16)r;
}
__device__ __forceinline__ float bf2f(u16 h) {
    return __uint_as_float(((u32)h) << 16);
}
__device__ __forceinline__ float fast_tanh(float x) {
    float t = __expf(2.0f * x);
    return 1.0f - __fdividef(2.0f, t + 1.0f);
}

// ---- cast bond_feat fp32 -> bf16 (8 elems/thread) ----
__global__ __launch_bounds__(256) void cast_bond(const float* __restrict__ x,
                                                 u16* __restrict__ y) {
    int i = blockIdx.x * 256 + threadIdx.x;
    if (i >= NN * DIM / 8) return;
    const float4* xv = (const float4*)x;
    float4 a = xv[2 * i], b = xv[2 * i + 1];
    uint4 o;
    o.x = (u32)f2bf(a.x) | ((u32)f2bf(a.y) << 16);
    o.y = (u32)f2bf(a.z) | ((u32)f2bf(a.w) << 16);
    o.z = (u32)f2bf(b.x) | ((u32)f2bf(b.y) << 16);
    o.w = (u32)f2bf(b.z) | ((u32)f2bf(b.w) << 16);
    ((uint4*)y)[i] = o;
}

// ---- pack W [4][256][128] fp32 -> WbT [8 slabs][128 out][128 in] bf16 ----
__global__ __launch_bounds__(256) void pack_w(const float* __restrict__ W,
                                              u16* __restrict__ WbT) {
    int i = blockIdx.x * 256 + threadIdx.x;  // 131072 total
    int d = i & 127;
    int o = (i >> 7) & 127;
    int st = i >> 14;  // slab
    WbT[i] = f2bf(W[(size_t)(st * 128 + d) * 128 + o]);
}

// ---- Y[slab][node][128] bf16 = bond @ Wslab (+bias on t==0 slabs) ----
__global__ __launch_bounds__(256) void gemm_y(const u16* __restrict__ bondB,
                                              const u16* __restrict__ WbT,
                                              const float* __restrict__ bias,
                                              u16* __restrict__ Y) {
    __shared__ __align__(16) u16 As[64 * LDA];
    __shared__ __align__(16) u16 Bs[128 * LDA];
    const int slab = blockIdx.y;
    const int node0 = blockIdx.x * 64;
    const int tid = threadIdx.x;

#pragma unroll
    for (int it = 0; it < 4; ++it) {
        int idx = it * 256 + tid;
        int row = idx >> 4, ch = idx & 15;
        int gr = node0 + row;
        if (gr >= NN) gr = NN - 1;
        *(uint4*)&As[row * LDA + ch * 8] = *(const uint4*)&bondB[(size_t)gr * DIM + ch * 8];
    }
    const u16* Wslab = WbT + (size_t)slab * DIM * DIM;
#pragma unroll
    for (int it = 0; it < 8; ++it) {
        int idx = it * 256 + tid;
        int row = idx >> 4, ch = idx & 15;
        *(uint4*)&Bs[row * LDA + ch * 8] = *(const uint4*)&Wslab[idx * 8];
    }
    __syncthreads();

    const int wave = tid >> 6, lane = tid & 63;
    const int m0 = wave * 16;
    const int lrow = lane & 15;
    const int lk8 = (lane >> 4) * 8;

    f32x4 acc[8] = {};
#pragma unroll
    for (int kk = 0; kk < 4; ++kk) {
        int ko = kk * 32 + lk8;
        bf16x8 a = *(const bf16x8*)&As[(m0 + lrow) * LDA + ko];
#pragma unroll
        for (int nb = 0; nb < 8; ++nb) {
            bf16x8 b = *(const bf16x8*)&Bs[(nb * 16 + lrow) * LDA + ko];
            acc[nb] = __builtin_amdgcn_mfma_f32_16x16x32_bf16(a, b, acc[nb], 0, 0, 0);
        }
    }

    const int k = slab >> 1, t = slab & 1;
    const int rbase = (lane >> 4) * 4;
#pragma unroll
    for (int nb = 0; nb < 8; ++nb) {
        int o = nb * 16 + lrow;
        float bv = (t == 0) ? bias[k * DIM + o] : 0.0f;
#pragma unroll
        for (int r = 0; r < 4; ++r) {
            int node = node0 + m0 + rbase + r;
            if (node < NN)
                Y[(size_t)slab * NN * DIM + (size_t)node * DIM + o] = f2bf(acc[nb][r] + bv);
        }
    }
}

// ==================== CSR build (counting sort by dst) ====================

__global__ __launch_bounds__(256) void hist_kernel(const int* __restrict__ ei,
                                                   int* __restrict__ counts) {
    int k = blockIdx.y;
    int e = blockIdx.x * 256 + threadIdx.x;
    if (e >= NE) return;
    int dst = ei[(size_t)(k * 2 + 1) * NE + e];
    atomicAdd(&counts[k * NN + dst], 1);
}

__global__ __launch_bounds__(256) void scan_reduce(const int* __restrict__ counts,
                                                   int* __restrict__ blockSums) {
    int b = blockIdx.x, t = threadIdx.x;
    int base = b * SCAN_CHUNK + t * 4;
    int s = 0;
#pragma unroll
    for (int u = 0; u < 4; ++u) {
        int i = base + u;
        if (i < NBINS) s += counts[i];
    }
    __shared__ int red[256];
    red[t] = s;
    __syncthreads();
    for (int off = 128; off > 0; off >>= 1) {
        if (t < off) red[t] += red[t + off];
        __syncthreads();
    }
    if (t == 0) blockSums[b] = red[0];
}

__global__ void scan_bases(int* __restrict__ blockSums, int* __restrict__ offsets) {
    __shared__ int lds[512];
    int t = threadIdx.x;
    lds[t] = (t < NBLK) ? blockSums[t] : 0;
    __syncthreads();
    if (t == 0) {
        int run = 0;
        for (int i = 0; i < NBLK; ++i) {
            int v = lds[i];
            lds[i] = run;
            run += v;
        }
        offsets[NBINS] = run;  // total = NA*NE
    }
    __syncthreads();
    if (t < NBLK) blockSums[t] = lds[t];
}

__global__ __launch_bounds__(256) void scan_write(const int* __restrict__ counts,
                                                  const int* __restrict__ blockBases,
                                                  int* __restrict__ offsets,
                                                  int* __restrict__ woff) {
    int b = blockIdx.x, t = threadIdx.x;
    int base = b * SCAN_CHUNK + t * 4;
    int v[4];
    int s = 0;
#pragma unroll
    for (int u = 0; u < 4; ++u) {
        int i = base + u;
        v[u] = (i < NBINS) ? counts[i] : 0;
        s += v[u];
    }
    __shared__ int lds[256];
    lds[t] = s;
    __syncthreads();
    for (int off = 1; off < 256; off <<= 1) {
        int add = (t >= off) ? lds[t - off] : 0;
        __syncthreads();
        lds[t] += add;
        __syncthreads();
    }
    int run = blockBases[b] + lds[t] - s;  // exclusive within block + block base
#pragma unroll
    for (int u = 0; u < 4; ++u) {
        int i = base + u;
        if (i < NBINS) {
            offsets[i] = run;
            woff[i] = run;
            run += v[u];
        }
    }
}

__global__ __launch_bounds__(256) void scatter_kernel(const int* __restrict__ ei,
                                                      int* __restrict__ woff,
                                                      int* __restrict__ sorted_src) {
    int k = blockIdx.y;
    int e = blockIdx.x * 256 + threadIdx.x;
    if (e >= NE) return;
    int src = ei[(size_t)(k * 2 + 0) * NE + e];
    int dst = ei[(size_t)(k * 2 + 1) * NE + e];
    int pos = atomicAdd(&woff[k * NN + dst], 1);
    sorted_src[pos] = src;
}

// ---- gather edge phase: one wave per (node, head), no atomics ----
__global__ __launch_bounds__(256) void gather_kernel(const int* __restrict__ offsets,
                                                     const int* __restrict__ sorted_src,
                                                     const u16* __restrict__ Y,
                                                     const u16* __restrict__ bondB,
                                                     float* __restrict__ out) {
    const int k = blockIdx.y;
    const int node = blockIdx.x * 4 + (threadIdx.x >> 6);
    const int lane = threadIdx.x & 63;
    const int f = lane * 2;
    const int bin = k * NN + node;
    int m = offsets[bin];
    const int end = offsets[bin + 1];

    const u32 y1 = *(const u32*)&Y[((size_t)(2 * k) * NN + node) * DIM + f];
    const float y1a = bf2f((u16)(y1 & 0xffffu));
    const float y1b = bf2f((u16)(y1 >> 16));
    float acc0 = 0.0f, acc1 = 0.0f;

    int src = (m < end) ? sorted_src[m] : 0;
    while (m < end) {
        int nsrc = (m + 1 < end) ? sorted_src[m + 1] : 0;
        const u32 y2 = *(const u32*)&Y[((size_t)(2 * k + 1) * NN + src) * DIM + f];
        const u32 xj = *(const u32*)&bondB[(size_t)src * DIM + f];
        float p0 = y1a + bf2f((u16)(y2 & 0xffffu));
        float p1 = y1b + bf2f((u16)(y2 >> 16));
        acc0 += fast_tanh(p0) * bf2f((u16)(xj & 0xffffu));
        acc1 += fast_tanh(p1) * bf2f((u16)(xj >> 16));
        src = nsrc;
        ++m;
    }
    *(float2*)&out[(size_t)node * (NA * DIM) + k * DIM + f] = make_float2(acc0, acc1);
}

// ---- legacy atomic edge kernel (mid fallback) ----
__global__ __launch_bounds__(256) void edge_kernel(const int* __restrict__ ei,
                                                   const u16* __restrict__ Y,
                                                   const float* __restrict__ bond,
                                                   float* __restrict__ out) {
    const int k = blockIdx.y;
    const int e = blockIdx.x * 4 + (threadIdx.x >> 6);
    const int lane = threadIdx.x & 63;
    const int src = ei[(size_t)(k * 2 + 0) * NE + e];
    const int dst = ei[(size_t)(k * 2 + 1) * NE + e];
    const int f = lane * 2;
    const u32 y1p = *(const u32*)&Y[((size_t)(k * 2 + 0) * NN + dst) * DIM + f];
    const u32 y2p = *(const u32*)&Y[((size_t)(k * 2 + 1) * NN + src) * DIM + f];
    const float2 xj = *(const float2*)&bond[(size_t)src * DIM + f];
    float p0 = bf2f((u16)(y1p & 0xffffu)) + bf2f((u16)(y2p & 0xffffu));
    float p1 = bf2f((u16)(y1p >> 16)) + bf2f((u16)(y2p >> 16));
    float a0 = fast_tanh(p0);
    float a1 = fast_tanh(p1);
    float* op = out + (size_t)dst * (NA * DIM) + k * DIM + f;
    atomicAdd(op, a0 * xj.x);
    atomicAdd(op + 1, a1 * xj.y);
}

// ---- ultra fallback: direct per-edge compute ----
__global__ __launch_bounds__(128) void fallback_edge(const float* __restrict__ bond,
                                                     const int* __restrict__ ei,
                                                     const float* __restrict__ W,
                                                     const float* __restrict__ bias,
                                                     float* __restrict__ out) {
    __shared__ float xi[DIM], xj[DIM];
    const int k = blockIdx.y;
    const int e = blockIdx.x;
    const int o = threadIdx.x;
    const int src = ei[(size_t)(k * 2 + 0) * NE + e];
    const int dst = ei[(size_t)(k * 2 + 1) * NE + e];
    xi[o] = bond[(size_t)dst * DIM + o];
    xj[o] = bond[(size_t)src * DIM + o];
    __syncthreads();
    const float* Wk = W + (size_t)k * 2 * DIM * DIM;
    float acc = bias[k * DIM + o];
    for (int din = 0; din < DIM; ++din) {
        acc += xi[din] * Wk[din * DIM + o];
        acc += xj[din] * Wk[(DIM + din) * DIM + o];
    }
    float alpha = fast_tanh(acc);
    atomicAdd(&out[(size_t)dst * (NA * DIM) + k * DIM + o], alpha * xj[o]);
}

static inline size_t align256(size_t x) { return (x + 255) & ~(size_t)255; }

extern "C" void kernel_launch(void* const* d_in, const int* in_sizes, int n_in,
                              void* d_out, int out_size, void* d_ws, size_t ws_size,
                              hipStream_t stream) {
    const float* bond = (const float*)d_in[0];
    const int* ei = (const int*)d_in[1];
    const float* W = (const float*)d_in[2];
    const float* bias = (const float*)d_in[3];
    float* out = (float*)d_out;

    const size_t wbt_bytes = align256((size_t)NA * 2 * DIM * DIM * 2);   // 256 KB
    const size_t bondb_bytes = align256((size_t)NN * DIM * 2);           // 25.6 MB
    const size_t y_bytes = align256((size_t)NA * 2 * NN * DIM * 2);      // 204.8 MB
    const size_t counts_bytes = align256((size_t)NBINS * 4);             // 1.6 MB
    const size_t offsets_bytes = align256(((size_t)NBINS + 1) * 4);      // 1.6 MB
    const size_t woff_bytes = align256((size_t)NBINS * 4);               // 1.6 MB
    const size_t bsum_bytes = align256((size_t)512 * 4);                 // 2 KB
    const size_t ssrc_bytes = align256((size_t)NA * NE * 4);             // 8 MB

    const size_t base_bytes = wbt_bytes + bondb_bytes + y_bytes;
    const size_t full_bytes = base_bytes + counts_bytes + offsets_bytes +
                              woff_bytes + bsum_bytes + ssrc_bytes;

    if (ws_size >= full_bytes) {
        char* p = (char*)d_ws;
        u16* WbT = (u16*)p;                 p += wbt_bytes;
        u16* bondB = (u16*)p;               p += bondb_bytes;
        u16* Y = (u16*)p;                   p += y_bytes;
        int* counts = (int*)p;              p += counts_bytes;
        int* offsets = (int*)p;             p += offsets_bytes;
        int* woff = (int*)p;                p += woff_bytes;
        int* bsum = (int*)p;                p += bsum_bytes;
        int* ssrc = (int*)p;

        // projections
        pack_w<<<dim3(131072 / 256), 256, 0, stream>>>(W, WbT);
        cast_bond<<<dim3((NN * DIM / 8 + 255) / 256), 256, 0, stream>>>(bond, bondB);
        gemm_y<<<dim3((NN + 63) / 64, NA * 2), 256, 0, stream>>>(bondB, WbT, bias, Y);

        // CSR build (overlaps gemm in-order on stream, all cheap)
        hipMemsetAsync(counts, 0, (size_t)NBINS * 4, stream);
        hist_kernel<<<dim3((NE + 255) / 256, NA), 256, 0, stream>>>(ei, counts);
        scan_reduce<<<dim3(NBLK), 256, 0, stream>>>(counts, bsum);
        scan_bases<<<dim3(1), 512, 0, stream>>>(bsum, offsets);
        scan_write<<<dim3(NBLK), 256, 0, stream>>>(counts, bsum, offsets, woff);
        scatter_kernel<<<dim3((NE + 255) / 256, NA), 256, 0, stream>>>(ei, woff, ssrc);

        // gather phase: one wave per (node, head); writes every output once
        gather_kernel<<<dim3(NN / 4, NA), 256, 0, stream>>>(offsets, ssrc, Y, bondB, out);
    } else if (ws_size >= base_bytes) {
        u16* WbT = (u16*)d_ws;
        u16* bondB = (u16*)((char*)d_ws + wbt_bytes);
        u16* Y = (u16*)((char*)d_ws + wbt_bytes + bondb_bytes);
        hipMemsetAsync(d_out, 0, (size_t)out_size * sizeof(float), stream);
        pack_w<<<dim3(131072 / 256), 256, 0, stream>>>(W, WbT);
        cast_bond<<<dim3((NN * DIM / 8 + 255) / 256), 256, 0, stream>>>(bond, bondB);
        gemm_y<<<dim3((NN + 63) / 64, NA * 2), 256, 0, stream>>>(bondB, WbT, bias, Y);
        edge_kernel<<<dim3(NE / 4, NA), 256, 0, stream>>>(ei, Y, bond, out);
    } else {
        hipMemsetAsync(d_out, 0, (size_t)out_size * sizeof(float), stream);
        fallback_edge<<<dim3(NE, NA), 128, 0, stream>>>(bond, ei, W, bias, out);
    }
}